// Round 4
// baseline (2680.990 us; speedup 1.0000x reference)
//
#include <hip/hip_runtime.h>
#include <math.h>

// SwinTransformer3D block, fp32 baseline, ws_size-adaptive chunking.
// B=8 T=8 H=56 W=56 C=128, window (2,7,7) -> N=98, shift (1,3,3), HEADS=4, d=32.
// TOK = 2048 windows * 98 = 200704 tokens.
//
// Scratch layout per call (chunk size CW windows, CTOK = CW*98 tokens):
//   trans @ 0                 : CTOK*512 floats  (attn: xw + qkv | mlp: h)
//   stats @ CTOK*512 floats   : TOK*2 floats     (LN2 mean/rstd)
// Required bytes = CW*200704 + 1,605,632.  CW picked at launch from ws_size:
//   2048 -> 412.6 MB, 512 -> 104.4 MB, 256 -> 53.0 MB, 64 -> 14.5 MB, 32 -> 8.0 MB.
// Residual y lives in d_out (proj writes it fully; FC2 does in-place add).

#define TOK 200704
#define SCALE_Q 0.17677669529663687f

// token (win*98+n) -> float offset of its ORIGINAL spatial position
// (window reverse + roll-back; also the gather map for LN1+roll+partition,
// since roll-back is the inverse shift).
__device__ __forceinline__ size_t spatial_off(int tok) {
    int win = tok / 98;
    int n = tok - win * 98;
    int b = win >> 8;          // 256 windows per batch element
    int widx = win & 255;
    int t_blk = widx >> 6;
    int h_blk = (widx >> 3) & 7;
    int w_blk = widx & 7;
    int tt = (n >= 49) ? 1 : 0;
    int r = n - tt * 49;
    int hh = r / 7;
    int ww = r - hh * 7;
    int t = t_blk * 2 + tt;
    int hc = h_blk * 7 + hh;
    int wc = w_blk * 7 + ww;
    int tf = (t + 1) & 7;              // roll back shift (1,3,3)
    int hf = hc + 3; if (hf >= 56) hf -= 56;
    int wf = wc + 3; if (wf >= 56) wf -= 56;
    return ((((size_t)b * 8 + tf) * 56 + hf) * 56 + wf) * 128;
}

// K1: LN1 + shifted roll + window partition (one chunk). One wave/token.
__global__ __launch_bounds__(256) void ln_win_k(const float* __restrict__ x,
                                                const float* __restrict__ g,
                                                const float* __restrict__ b,
                                                float* __restrict__ xw,
                                                int tok_base) {
    int ltok = blockIdx.x * 4 + (threadIdx.x >> 6);
    int lane = threadIdx.x & 63;
    const float* src = x + spatial_off(tok_base + ltok);
    float2 v = *(const float2*)(src + lane * 2);
    float s = v.x + v.y;
    float q = v.x * v.x + v.y * v.y;
#pragma unroll
    for (int o = 32; o > 0; o >>= 1) {
        s += __shfl_xor(s, o);
        q += __shfl_xor(q, o);
    }
    float mean = s * 0.0078125f;
    float var = q * 0.0078125f - mean * mean;
    float rstd = rsqrtf(var + 1e-5f);
    float2 gv = *(const float2*)(g + lane * 2);
    float2 bv = *(const float2*)(b + lane * 2);
    float2 o2;
    o2.x = (v.x - mean) * rstd * gv.x + bv.x;
    o2.y = (v.y - mean) * rstd * gv.y + bv.y;
    *(float2*)(xw + (size_t)ltok * 128 + lane * 2) = o2;
}

// per-token LN2 stats (mean, rstd) over y rows (y == d_out), full TOK.
__global__ __launch_bounds__(256) void stats_k(const float* __restrict__ y,
                                               float* __restrict__ st) {
    int tok = blockIdx.x * 4 + (threadIdx.x >> 6);
    int lane = threadIdx.x & 63;
    float2 v = *(const float2*)(y + (size_t)tok * 128 + lane * 2);
    float s = v.x + v.y;
    float q = v.x * v.x + v.y * v.y;
#pragma unroll
    for (int o = 32; o > 0; o >>= 1) {
        s += __shfl_xor(s, o);
        q += __shfl_xor(q, o);
    }
    float mean = s * 0.0078125f;
    float var = q * 0.0078125f - mean * mean;
    float rstd = rsqrtf(var + 1e-5f);
    if (lane == 0) {
        float2 o2; o2.x = mean; o2.y = rstd;
        *(float2*)(st + 2 * tok) = o2;
    }
}

// Tiled fp32 GEMM on one chunk: C[M,N] = A[M,K] @ W[N,K]^T + bias.
// MODE 0 = QKV scatter (+q scale) to per-(window,head) layout (chunk-local),
// MODE 1 = proj (+x residual, spatial scatter to y=d_out; uses row_off),
// MODE 2 = fc1 (LN2 on A-load from stats, GELU out; A/E0 pre-offset),
// MODE 3 = fc2 (+y residual in-place; A/E0/O pre-offset).
template <int MODE, int K>
__global__ __launch_bounds__(256) void gemm_k(const float* __restrict__ A,
                                              const float* __restrict__ W,
                                              const float* __restrict__ bias,
                                              float* __restrict__ O,
                                              const float* __restrict__ E0,
                                              const float* __restrict__ E1,
                                              const float* __restrict__ E2,
                                              int row_off, int ctok) {
    __shared__ float As[32][68];  // transposed, +4 pad
    __shared__ float Bs[32][68];
    int mb = blockIdx.x, nb = blockIdx.y;
    int tid = threadIdx.x;
    int tx = tid & 15, ty = tid >> 4;
    int m0 = ty * 4, n0 = tx * 4;
    float acc[4][4];
#pragma unroll
    for (int i = 0; i < 4; i++)
#pragma unroll
        for (int j = 0; j < 4; j++) acc[i][j] = 0.f;

    const float* Ab = A + (size_t)mb * 64 * K;
    const float* Wb = W + (size_t)nb * 64 * K;

    for (int k0 = 0; k0 < K; k0 += 32) {
#pragma unroll
        for (int i = 0; i < 2; i++) {
            int f = tid + i * 256;
            int r = f >> 3;
            int kc = (f & 7) << 2;
            float4 av = *(const float4*)(Ab + (size_t)r * K + k0 + kc);
            if constexpr (MODE == 2) {  // LN2 applied on load
                int lrow = mb * 64 + r;
                float mean = E0[2 * lrow], rstd = E0[2 * lrow + 1];
                float4 g4 = *(const float4*)(E1 + k0 + kc);
                float4 b4 = *(const float4*)(E2 + k0 + kc);
                av.x = (av.x - mean) * rstd * g4.x + b4.x;
                av.y = (av.y - mean) * rstd * g4.y + b4.y;
                av.z = (av.z - mean) * rstd * g4.z + b4.z;
                av.w = (av.w - mean) * rstd * g4.w + b4.w;
            }
            As[kc + 0][r] = av.x; As[kc + 1][r] = av.y;
            As[kc + 2][r] = av.z; As[kc + 3][r] = av.w;
            float4 wv = *(const float4*)(Wb + (size_t)r * K + k0 + kc);
            Bs[kc + 0][r] = wv.x; Bs[kc + 1][r] = wv.y;
            Bs[kc + 2][r] = wv.z; Bs[kc + 3][r] = wv.w;
        }
        __syncthreads();
#pragma unroll
        for (int k = 0; k < 32; k++) {
            float4 a4 = *(const float4*)&As[k][m0];
            float4 b4 = *(const float4*)&Bs[k][n0];
            float av_[4] = {a4.x, a4.y, a4.z, a4.w};
            float bv_[4] = {b4.x, b4.y, b4.z, b4.w};
#pragma unroll
            for (int i = 0; i < 4; i++)
#pragma unroll
                for (int j = 0; j < 4; j++)
                    acc[i][j] = fmaf(av_[i], bv_[j], acc[i][j]);
        }
        __syncthreads();
    }

    int colb = nb * 64 + n0;
    float4 bv4 = *(const float4*)(bias + colb);
#pragma unroll
    for (int i = 0; i < 4; i++) {
        int lrow = mb * 64 + m0 + i;
        float4 r4;
        r4.x = acc[i][0] + bv4.x;
        r4.y = acc[i][1] + bv4.y;
        r4.z = acc[i][2] + bv4.z;
        r4.w = acc[i][3] + bv4.w;
        if constexpr (MODE == 0) {
            int which = colb >> 7;          // 0=q 1=k 2=v
            int head = (colb & 127) >> 5;
            int dd = colb & 31;
            if (which == 0) { r4.x *= SCALE_Q; r4.y *= SCALE_Q; r4.z *= SCALE_Q; r4.w *= SCALE_Q; }
            int lwin = lrow / 98;
            int n = lrow - lwin * 98;
            *(float4*)(O + (size_t)which * ((size_t)ctok * 128) +
                       (((size_t)(lwin * 4 + head) * 98 + n) * 32 + dd)) = r4;
        } else if constexpr (MODE == 1) {
            size_t soff = spatial_off(row_off + lrow) + colb;
            const float4 xv = *(const float4*)(E0 + soff);
            r4.x += xv.x; r4.y += xv.y; r4.z += xv.z; r4.w += xv.w;
            *(float4*)(O + soff) = r4;
        } else if constexpr (MODE == 2) {
            r4.x = 0.5f * r4.x * (1.f + erff(r4.x * 0.70710678118654752f));
            r4.y = 0.5f * r4.y * (1.f + erff(r4.y * 0.70710678118654752f));
            r4.z = 0.5f * r4.z * (1.f + erff(r4.z * 0.70710678118654752f));
            r4.w = 0.5f * r4.w * (1.f + erff(r4.w * 0.70710678118654752f));
            *(float4*)(O + (size_t)lrow * 512 + colb) = r4;
        } else {
            const float4 yv = *(const float4*)(E0 + (size_t)lrow * 128 + colb);
            r4.x += yv.x; r4.y += yv.y; r4.z += yv.z; r4.w += yv.w;
            *(float4*)(O + (size_t)lrow * 128 + colb) = r4;
        }
    }
}

// K3: per-(window,head) attention, chunk-local. 256 threads.
// LDS (floats): qs stride 36 @0, ks stride 36 @3528, vs stride 32 @7056,
// S stride 100 @10192. Total 19992 floats = 79.97 KB -> 2 blocks/CU.
// Register-tile reads for logical rows 98..111 alias later smem regions
// (garbage, in-bounds); results discarded by <98 guards.
__global__ __launch_bounds__(256) void attn_k(const float* __restrict__ Q,
                                              const float* __restrict__ Kg,
                                              const float* __restrict__ V,
                                              const float* __restrict__ mask,
                                              const float* __restrict__ rpb,
                                              float* __restrict__ O,
                                              int win_off) {
    __shared__ float smem[19992];
    const int KS = 3528, VS = 7056, SBASE = 10192;
    int wh = blockIdx.x;           // chunk-local (window,head)
    int lwin = wh >> 2, head = wh & 3;
    int widx = (win_off + lwin) & 255;   // 256 windows per batch element
    int tid = threadIdx.x;
    {
        const float4* qp = (const float4*)(Q + (size_t)wh * 3136);
        const float4* kp = (const float4*)(Kg + (size_t)wh * 3136);
        const float4* vp = (const float4*)(V + (size_t)wh * 3136);
        for (int f = tid; f < 784; f += 256) {
            int n = f >> 3, dc = (f & 7) << 2;
            *(float4*)&smem[n * 36 + dc] = qp[f];
            *(float4*)&smem[KS + n * 36 + dc] = kp[f];
            ((float4*)&smem[VS])[f] = vp[f];
        }
    }
    __syncthreads();

    int tx = tid & 15, ty = tid >> 4;
    // ---- S = q k^T (7x7 register tile over 112x112 logical grid) ----
    float sacc[7][7];
#pragma unroll
    for (int a = 0; a < 7; a++)
#pragma unroll
        for (int b = 0; b < 7; b++) sacc[a][b] = 0.f;
#pragma unroll
    for (int d0 = 0; d0 < 32; d0 += 4) {
        float4 qv[7], kv[7];
#pragma unroll
        for (int a = 0; a < 7; a++) qv[a] = *(const float4*)&smem[(16 * a + ty) * 36 + d0];
#pragma unroll
        for (int b = 0; b < 7; b++) kv[b] = *(const float4*)&smem[KS + (16 * b + tx) * 36 + d0];
#pragma unroll
        for (int a = 0; a < 7; a++)
#pragma unroll
            for (int b = 0; b < 7; b++) {
                sacc[a][b] = fmaf(qv[a].x, kv[b].x, sacc[a][b]);
                sacc[a][b] = fmaf(qv[a].y, kv[b].y, sacc[a][b]);
                sacc[a][b] = fmaf(qv[a].z, kv[b].z, sacc[a][b]);
                sacc[a][b] = fmaf(qv[a].w, kv[b].w, sacc[a][b]);
            }
    }
    int tn[7], hn[7], wn[7], tm[7], hm[7], wm[7];
#pragma unroll
    for (int a = 0; a < 7; a++) {
        int n = 16 * a + ty;
        int t_ = (n >= 49) ? 1 : 0; int r = n - t_ * 49;
        int h7 = r / 7;
        tn[a] = t_; hn[a] = h7; wn[a] = r - h7 * 7;
        int m = 16 * a + tx;
        int t2 = (m >= 49) ? 1 : 0; int r2 = m - t2 * 49;
        int h72 = r2 / 7;
        tm[a] = t2; hm[a] = h72; wm[a] = r2 - h72 * 7;
    }
    const float* mrow = mask + (size_t)widx * 9604;
#pragma unroll
    for (int a = 0; a < 7; a++) {
        int n = 16 * a + ty;
        if (n < 98) {
#pragma unroll
            for (int b = 0; b < 7; b++) {
                int m = 16 * b + tx;
                if (m < 98) {
                    int bidx = (tn[a] - tm[b] + 1) * 169 + (hn[a] - hm[b] + 6) * 13 +
                               (wn[a] - wm[b] + 6);
                    smem[SBASE + n * 100 + m] = sacc[a][b] + rpb[bidx * 4 + head] + mrow[n * 98 + m];
                }
            }
        }
    }
    __syncthreads();

    // ---- softmax: one wave per row group ----
    int wv = tid >> 6, lane = tid & 63;
    for (int i = 0; i < 25; i++) {
        int n = wv + 4 * i;
        if (n < 98) {
            float v1 = smem[SBASE + n * 100 + lane];
            float v2 = (lane < 34) ? smem[SBASE + n * 100 + 64 + lane] : -3.4e38f;
            float mx = fmaxf(v1, v2);
#pragma unroll
            for (int o = 32; o > 0; o >>= 1) mx = fmaxf(mx, __shfl_xor(mx, o));
            float p1 = __expf(v1 - mx);
            float p2 = (lane < 34) ? __expf(v2 - mx) : 0.f;
            float sm = p1 + p2;
#pragma unroll
            for (int o = 32; o > 0; o >>= 1) sm += __shfl_xor(sm, o);
            float inv = 1.f / sm;
            smem[SBASE + n * 100 + lane] = p1 * inv;
            if (lane < 34) smem[SBASE + n * 100 + 64 + lane] = p2 * inv;
        }
    }
    __syncthreads();

    // ---- O = P V ----
    float oacc[7][2];
#pragma unroll
    for (int a = 0; a < 7; a++) { oacc[a][0] = 0.f; oacc[a][1] = 0.f; }
    for (int mc = 0; mc < 96; mc += 4) {
        float2 vv[4];
#pragma unroll
        for (int u = 0; u < 4; u++) vv[u] = *(const float2*)&smem[VS + (mc + u) * 32 + tx * 2];
#pragma unroll
        for (int a = 0; a < 7; a++) {
            if (a < 6 || ty < 2) {
                int n = 16 * a + ty;
                float4 p4 = *(const float4*)&smem[SBASE + n * 100 + mc];
                oacc[a][0] = fmaf(p4.x, vv[0].x, oacc[a][0]);
                oacc[a][1] = fmaf(p4.x, vv[0].y, oacc[a][1]);
                oacc[a][0] = fmaf(p4.y, vv[1].x, oacc[a][0]);
                oacc[a][1] = fmaf(p4.y, vv[1].y, oacc[a][1]);
                oacc[a][0] = fmaf(p4.z, vv[2].x, oacc[a][0]);
                oacc[a][1] = fmaf(p4.z, vv[2].y, oacc[a][1]);
                oacc[a][0] = fmaf(p4.w, vv[3].x, oacc[a][0]);
                oacc[a][1] = fmaf(p4.w, vv[3].y, oacc[a][1]);
            }
        }
    }
#pragma unroll
    for (int m = 96; m < 98; m++) {
        float2 vv = *(const float2*)&smem[VS + m * 32 + tx * 2];
#pragma unroll
        for (int a = 0; a < 7; a++) {
            if (a < 6 || ty < 2) {
                int n = 16 * a + ty;
                float p = smem[SBASE + n * 100 + m];
                oacc[a][0] = fmaf(p, vv.x, oacc[a][0]);
                oacc[a][1] = fmaf(p, vv.y, oacc[a][1]);
            }
        }
    }
#pragma unroll
    for (int a = 0; a < 7; a++) {
        int n = 16 * a + ty;
        if (n < 98) {
            float2 o2; o2.x = oacc[a][0]; o2.y = oacc[a][1];
            *(float2*)&O[((size_t)(lwin * 98 + n)) * 128 + head * 32 + tx * 2] = o2;
        }
    }
}

extern "C" void kernel_launch(void* const* d_in, const int* in_sizes, int n_in,
                              void* d_out, int out_size, void* d_ws, size_t ws_size,
                              hipStream_t stream) {
    const float* x      = (const float*)d_in[0];
    const float* mask   = (const float*)d_in[1];
    const float* ln1_g  = (const float*)d_in[2];
    const float* ln1_b  = (const float*)d_in[3];
    const float* qkv_w  = (const float*)d_in[4];
    const float* qkv_b  = (const float*)d_in[5];
    const float* rpb    = (const float*)d_in[6];
    const float* proj_w = (const float*)d_in[7];
    const float* proj_b = (const float*)d_in[8];
    const float* ln2_g  = (const float*)d_in[9];
    const float* ln2_b  = (const float*)d_in[10];
    const float* fc1_w  = (const float*)d_in[11];
    const float* fc1_b  = (const float*)d_in[12];
    const float* fc2_w  = (const float*)d_in[13];
    const float* fc2_b  = (const float*)d_in[14];
    float* out = (float*)d_out;          // doubles as residual buffer y

    // ---- pick chunk size from ws_size (fixed across calls -> same schedule) ----
    int CW = 32;
    {
        const int tiers[5] = {2048, 512, 256, 64, 32};
        for (int i = 0; i < 5; i++) {
            size_t need = (size_t)tiers[i] * 200704u + 1605632u;
            if (ws_size >= need) { CW = tiers[i]; break; }
        }
    }
    const int nch = 2048 / CW;
    const int ctok = CW * 98;

    float* trans = (float*)d_ws;
    float* stats = trans + (size_t)ctok * 512;
    float* xwc   = trans;                              // ctok*128
    float* qkvc  = trans + (size_t)ctok * 128;         // 3*ctok*128
    float* hc    = trans;                              // ctok*512 (reuse)
    float* Qc = qkvc;
    float* Kc = qkvc + (size_t)ctok * 128;
    float* Vc = qkvc + (size_t)ctok * 256;

    // ---- attention pipeline ----
    for (int c = 0; c < nch; c++) {
        int row_off = c * ctok;
        ln_win_k<<<ctok / 4, 256, 0, stream>>>(x, ln1_g, ln1_b, xwc, row_off);
        gemm_k<0, 128><<<dim3(ctok / 64, 6), 256, 0, stream>>>(
            xwc, qkv_w, qkv_b, qkvc, nullptr, nullptr, nullptr, 0, ctok);
        attn_k<<<CW * 4, 256, 0, stream>>>(Qc, Kc, Vc, mask, rpb, xwc, c * CW);
        gemm_k<1, 128><<<dim3(ctok / 64, 2), 256, 0, stream>>>(
            xwc, proj_w, proj_b, out, x, nullptr, nullptr, row_off, ctok);
    }

    // ---- LN2 stats over full y (= d_out) ----
    stats_k<<<TOK / 4, 256, 0, stream>>>(out, stats);

    // ---- MLP ----
    for (int c = 0; c < nch; c++) {
        int row_off = c * ctok;
        gemm_k<2, 128><<<dim3(ctok / 64, 8), 256, 0, stream>>>(
            out + (size_t)row_off * 128, fc1_w, fc1_b, hc,
            stats + 2 * (size_t)row_off, ln2_g, ln2_b, 0, ctok);
        gemm_k<3, 512><<<dim3(ctok / 64, 2), 256, 0, stream>>>(
            hc, fc2_w, fc2_b, out + (size_t)row_off * 128,
            out + (size_t)row_off * 128, nullptr, nullptr, 0, ctok);
    }
}

// Round 6
// 704.045 us; speedup vs baseline: 3.8080x; 3.8080x over previous
//
#include <hip/hip_runtime.h>
#include <hip/hip_bf16.h>
#include <math.h>

// SwinTransformer3D block, bf16-MFMA version (staging fix of round-5 kernel).
// B=8 T=8 H=56 W=56 C=128, window (2,7,7) -> N=98 (pad 112), shift (1,3,3),
// HEADS=4, d=32. TOK = 2048*98 = 200704 tokens, BWH = 8192 (win,head) pairs.
//
// ws layout (bytes), total 257,295,360 (~245 MiB):
//   P0 = 0          : xw / attnO / xn2 (bf16 TOK*128), reused serially
//   P1 = 51,381,248 : q  bf16 [bwh*98+n][32] (+1KB pad)
//   P2 = P1+51,381,248 : k  bf16 same (+pad)
//   P3 = P2+51,381,248 : Vt bf16 [bwh*32+d][112]
//   h  @ P1         : bf16 TOK*512 (q/k/Vt dead by then)
//   PW = P1+205,520,896 : bf16 weights (qkv/proj/fc1/fc2)
// Residual y lives in d_out (fp32); fc2 does in-place add.

#define TOK 200704
#define SCALE_Q 0.17677669529663687f

typedef __attribute__((ext_vector_type(8))) short bf16x8;
typedef __attribute__((ext_vector_type(4))) float f32x4;

__device__ __forceinline__ short f2b(float f) {
    __hip_bfloat16 h = __float2bfloat16(f);
    return *reinterpret_cast<short*>(&h);
}

// token (win*98+n) -> float offset of its ORIGINAL spatial position
// (window reverse + roll-back; also the gather map for LN1+roll+partition).
__device__ __forceinline__ size_t spatial_off(int tok) {
    int win = tok / 98;
    int n = tok - win * 98;
    int b = win >> 8;
    int widx = win & 255;
    int t_blk = widx >> 6;
    int h_blk = (widx >> 3) & 7;
    int w_blk = widx & 7;
    int tt = (n >= 49) ? 1 : 0;
    int r = n - tt * 49;
    int hh = r / 7;
    int ww = r - hh * 7;
    int t = t_blk * 2 + tt;
    int hc = h_blk * 7 + hh;
    int wc = w_blk * 7 + ww;
    int tf = (t + 1) & 7;
    int hf = hc + 3; if (hf >= 56) hf -= 56;
    int wf = wc + 3; if (wf >= 56) wf -= 56;
    return ((((size_t)b * 8 + tf) * 56 + hf) * 56 + wf) * 128;
}

// fp32 -> bf16 convert (weights)
__global__ __launch_bounds__(256) void cvt_k(const float* __restrict__ s,
                                             short* __restrict__ d, int n) {
    int i = blockIdx.x * 256 + threadIdx.x;
    if (i < n) d[i] = f2b(s[i]);
}

// LayerNorm (one wave per token, 2 ch/lane) -> bf16 output.
// WIN=1: gather input via spatial_off (LN1 + roll + window partition).
template <int WIN>
__global__ __launch_bounds__(256) void ln_k(const float* __restrict__ src,
                                            const float* __restrict__ g,
                                            const float* __restrict__ b,
                                            short* __restrict__ dst) {
    int tok = blockIdx.x * 4 + (threadIdx.x >> 6);
    int lane = threadIdx.x & 63;
    const float* sp = WIN ? (src + spatial_off(tok)) : (src + (size_t)tok * 128);
    float2 v = *(const float2*)(sp + lane * 2);
    float s = v.x + v.y;
    float q = v.x * v.x + v.y * v.y;
#pragma unroll
    for (int o = 32; o > 0; o >>= 1) {
        s += __shfl_xor(s, o);
        q += __shfl_xor(q, o);
    }
    float mean = s * 0.0078125f;
    float var = q * 0.0078125f - mean * mean;
    float rstd = rsqrtf(var + 1e-5f);
    float2 gv = *(const float2*)(g + lane * 2);
    float2 bv = *(const float2*)(b + lane * 2);
    short2 o2;
    o2.x = f2b((v.x - mean) * rstd * gv.x + bv.x);
    o2.y = f2b((v.y - mean) * rstd * gv.y + bv.y);
    *(short2*)(dst + (size_t)tok * 128 + lane * 2) = o2;
}

// bf16 MFMA GEMM: C[M,N] = A[M,K] @ W[N,K]^T + bias. 128x128 tile, 4 waves.
// LDS staging: srow=tid>>2 (0..63), scol=(tid&3)*8; two row passes (srow,
// srow+64) x one bf16x8 each -> full 128x32 tile (4096 shorts). 4 adjacent
// lanes form a contiguous 64B global segment.
// MODE 0: QKV -> q,k (bf16 [bwh*98+n][32], q scaled) + Vt (bf16 [bwh*32+d][112])
// MODE 1: proj + x residual, spatial scatter -> y (fp32, = d_out)
// MODE 2: fc1 + GELU -> h bf16
// MODE 3: fc2 + y residual (in-place) -> d_out fp32
template <int MODE, int KDIM>
__global__ __launch_bounds__(256) void mgemm(const short* __restrict__ A,
                                             const short* __restrict__ Wt,
                                             const float* __restrict__ bias,
                                             void* __restrict__ Optr,
                                             const float* __restrict__ E0,
                                             short* __restrict__ O2,
                                             short* __restrict__ O3) {
    __shared__ short As[128 * 40];
    __shared__ short Ws[128 * 40];
    const int tid = threadIdx.x;
    const int nb = blockIdx.x, mb = blockIdx.y;
    const int lane = tid & 63;
    const int wid = tid >> 6;
    const int wr = wid >> 1, wc = wid & 1;
    const int l15 = lane & 15, kg = lane >> 4;

    f32x4 zf = {0.f, 0.f, 0.f, 0.f};
    f32x4 acc[4][4];
#pragma unroll
    for (int i = 0; i < 4; i++)
#pragma unroll
        for (int j = 0; j < 4; j++) acc[i][j] = zf;

    const int srow = tid >> 2;          // 0..63
    const int scol = (tid & 3) * 8;     // 0,8,16,24
    const short* Ag = A + (size_t)(mb * 128 + srow) * KDIM + scol;
    const short* Wg = Wt + (size_t)(nb * 128 + srow) * KDIM + scol;
    const size_t half = (size_t)64 * KDIM;

    for (int k0 = 0; k0 < KDIM; k0 += 32) {
        *(bf16x8*)&As[srow * 40 + scol] = *(const bf16x8*)(Ag + k0);
        *(bf16x8*)&As[(srow + 64) * 40 + scol] = *(const bf16x8*)(Ag + half + k0);
        *(bf16x8*)&Ws[srow * 40 + scol] = *(const bf16x8*)(Wg + k0);
        *(bf16x8*)&Ws[(srow + 64) * 40 + scol] = *(const bf16x8*)(Wg + half + k0);
        __syncthreads();
        bf16x8 af[4], bfr[4];
#pragma unroll
        for (int mi = 0; mi < 4; mi++)
            af[mi] = *(const bf16x8*)&As[(wr * 64 + mi * 16 + l15) * 40 + kg * 8];
#pragma unroll
        for (int ni = 0; ni < 4; ni++)
            bfr[ni] = *(const bf16x8*)&Ws[(wc * 64 + ni * 16 + l15) * 40 + kg * 8];
#pragma unroll
        for (int mi = 0; mi < 4; mi++)
#pragma unroll
            for (int ni = 0; ni < 4; ni++)
                acc[mi][ni] = __builtin_amdgcn_mfma_f32_16x16x32_bf16(
                    af[mi], bfr[ni], acc[mi][ni], 0, 0, 0);
        __syncthreads();
    }

#pragma unroll
    for (int mi = 0; mi < 4; mi++) {
#pragma unroll
        for (int r = 0; r < 4; r++) {
            int gr = mb * 128 + wr * 64 + mi * 16 + kg * 4 + r;
            size_t so = 0;
            if constexpr (MODE == 1) so = spatial_off(gr);
#pragma unroll
            for (int ni = 0; ni < 4; ni++) {
                int gc = nb * 128 + wc * 64 + ni * 16 + l15;
                float v = acc[mi][ni][r] + bias[gc];
                if constexpr (MODE == 0) {
                    int which = gc >> 7;
                    int head = (gc >> 5) & 3;
                    int dd = gc & 31;
                    int lwin = gr / 98;
                    int n = gr - lwin * 98;
                    size_t bwh = (size_t)lwin * 4 + head;
                    if (which == 0) {
                        ((short*)Optr)[(bwh * 98 + n) * 32 + dd] = f2b(v * SCALE_Q);
                    } else if (which == 1) {
                        O2[(bwh * 98 + n) * 32 + dd] = f2b(v);
                    } else {
                        O3[(bwh * 32 + dd) * 112 + n] = f2b(v);
                    }
                } else if constexpr (MODE == 1) {
                    float* Of = (float*)Optr;
                    Of[so + gc] = v + E0[so + gc];
                } else if constexpr (MODE == 2) {
                    v = 0.5f * v * (1.f + erff(v * 0.70710678118654752f));
                    ((short*)Optr)[(size_t)gr * 512 + gc] = f2b(v);
                } else {
                    float* Of = (float*)Optr;
                    size_t o = (size_t)gr * 128 + gc;
                    Of[o] = v + Of[o];
                }
            }
        }
    }
}

// Attention: block = window (4 waves = 4 heads). N=98 padded to 112.
// Q/K fragments loaded directly from global ([bwh*98+n][32] bf16, contiguous
// 16B per lane); V fragments from pre-transposed Vt ([bwh*32+d][112]).
// S = QK^T via 7 MFMAs per 16-row band; bias from LDS-staged rpb column;
// mask computed analytically; wave-parallel softmax (shfl over 16-lane
// groups); P -> per-wave LDS tile (stride 136); PV = 8 MFMAs.
__global__ __launch_bounds__(256) void attn_k(const short* __restrict__ Qb,
                                              const short* __restrict__ Kb,
                                              const short* __restrict__ Vt,
                                              const float* __restrict__ rpb,
                                              short* __restrict__ O) {
    __shared__ short P_lds[4][16 * 136];
    __shared__ float rbias[4][508];
    const int win = blockIdx.x;
    const int tid = threadIdx.x;
    const int head = tid >> 6;
    const int lane = tid & 63;
    const int l15 = lane & 15, kg = lane >> 4;
    const size_t bwh = (size_t)win * 4 + head;
    const int widx = win & 255;
    const int t_blk = widx >> 6, h_blk = (widx >> 3) & 7, w_blk = widx & 7;
    short* Pw = P_lds[head];

    for (int i = lane; i < 507; i += 64) rbias[head][i] = rpb[i * 4 + head];
#pragma unroll
    for (int i = 0; i < 4; i++) {
        int idx = lane * 4 + i;
        Pw[(idx >> 4) * 136 + 112 + (idx & 15)] = 0;
    }

    const short* Kg = Kb + bwh * 3136;
    bf16x8 kf[7];
#pragma unroll
    for (int b = 0; b < 7; b++)
        kf[b] = *(const bf16x8*)(Kg + (b * 16 + l15) * 32 + kg * 8);
    const short* Vg = Vt + bwh * 3584;
    bf16x8 vf[2][4];
#pragma unroll
    for (int nt = 0; nt < 2; nt++)
#pragma unroll
        for (int ks = 0; ks < 4; ks++)
            vf[nt][ks] = *(const bf16x8*)(Vg + (nt * 16 + l15) * 112 + ks * 32 + kg * 8);

    int cm_t[7], cm_h[7], cm_w[7], creg[7];
    bool cvalid[7];
#pragma unroll
    for (int b = 0; b < 7; b++) {
        int n = b * 16 + l15;
        cvalid[b] = (n < 98);
        int nn = cvalid[b] ? n : 0;
        int tt = (nn >= 49) ? 1 : 0;
        int r = nn - tt * 49;
        int hh = r / 7;
        int ww = r - hh * 7;
        cm_t[b] = tt; cm_h[b] = hh; cm_w[b] = ww;
        int ct = (t_blk == 3) ? (1 + tt) : 0;
        int ch = (h_blk == 7) ? ((hh <= 3) ? 1 : 2) : 0;
        int cw = (w_blk == 7) ? ((ww <= 3) ? 1 : 2) : 0;
        creg[b] = ct * 9 + ch * 3 + cw;
    }

    const short* Qg = Qb + bwh * 3136;
    f32x4 zf = {0.f, 0.f, 0.f, 0.f};

    for (int a = 0; a < 7; a++) {
        bf16x8 qf = *(const bf16x8*)(Qg + (a * 16 + l15) * 32 + kg * 8);
        f32x4 s[7];
#pragma unroll
        for (int b = 0; b < 7; b++)
            s[b] = __builtin_amdgcn_mfma_f32_16x16x32_bf16(qf, kf[b], zf, 0, 0, 0);

        float p[7][4], mx[4], sm[4];
#pragma unroll
        for (int r = 0; r < 4; r++) {
            int m = a * 16 + kg * 4 + r;
            int mm = (m < 98) ? m : 0;
            int tt = (mm >= 49) ? 1 : 0;
            int rr = mm - tt * 49;
            int hh = rr / 7;
            int ww = rr - hh * 7;
            int ct = (t_blk == 3) ? (1 + tt) : 0;
            int ch = (h_blk == 7) ? ((hh <= 3) ? 1 : 2) : 0;
            int cw = (w_blk == 7) ? ((ww <= 3) ? 1 : 2) : 0;
            int rreg = ct * 9 + ch * 3 + cw;
            float mxv = -1e30f;
#pragma unroll
            for (int b = 0; b < 7; b++) {
                float v;
                if (cvalid[b]) {
                    int bidx = (tt - cm_t[b] + 1) * 169 + (hh - cm_h[b] + 6) * 13 +
                               (ww - cm_w[b] + 6);
                    v = s[b][r] + rbias[head][bidx] +
                        ((rreg == creg[b]) ? 0.f : -100.f);
                } else {
                    v = -1e30f;
                }
                p[b][r] = v;
                mxv = fmaxf(mxv, v);
            }
            mx[r] = mxv;
        }
#pragma unroll
        for (int r = 0; r < 4; r++) {
#pragma unroll
            for (int off = 1; off < 16; off <<= 1)
                mx[r] = fmaxf(mx[r], __shfl_xor(mx[r], off));
        }
#pragma unroll
        for (int r = 0; r < 4; r++) {
            float ss = 0.f;
#pragma unroll
            for (int b = 0; b < 7; b++) {
                float e = __expf(p[b][r] - mx[r]);
                p[b][r] = e;
                ss += e;
            }
            sm[r] = ss;
        }
#pragma unroll
        for (int r = 0; r < 4; r++) {
#pragma unroll
            for (int off = 1; off < 16; off <<= 1) sm[r] += __shfl_xor(sm[r], off);
        }
#pragma unroll
        for (int r = 0; r < 4; r++) {
            float inv = 1.f / sm[r];
#pragma unroll
            for (int b = 0; b < 7; b++)
                Pw[(kg * 4 + r) * 136 + b * 16 + l15] = f2b(p[b][r] * inv);
        }
        asm volatile("" ::: "memory");

        bf16x8 pa[4];
#pragma unroll
        for (int ks = 0; ks < 4; ks++)
            pa[ks] = *(const bf16x8*)&Pw[l15 * 136 + ks * 32 + kg * 8];
        f32x4 o0 = zf, o1 = zf;
#pragma unroll
        for (int ks = 0; ks < 4; ks++) {
            o0 = __builtin_amdgcn_mfma_f32_16x16x32_bf16(pa[ks], vf[0][ks], o0, 0, 0, 0);
            o1 = __builtin_amdgcn_mfma_f32_16x16x32_bf16(pa[ks], vf[1][ks], o1, 0, 0, 0);
        }
        asm volatile("" ::: "memory");
#pragma unroll
        for (int r = 0; r < 4; r++) {
            int m = a * 16 + kg * 4 + r;
            if (m < 98) {
                size_t base = ((size_t)win * 98 + m) * 128 + head * 32;
                O[base + l15] = f2b(o0[r]);
                O[base + 16 + l15] = f2b(o1[r]);
            }
        }
    }
}

extern "C" void kernel_launch(void* const* d_in, const int* in_sizes, int n_in,
                              void* d_out, int out_size, void* d_ws, size_t ws_size,
                              hipStream_t stream) {
    const float* x      = (const float*)d_in[0];
    const float* ln1_g  = (const float*)d_in[2];
    const float* ln1_b  = (const float*)d_in[3];
    const float* qkv_w  = (const float*)d_in[4];
    const float* qkv_b  = (const float*)d_in[5];
    const float* rpb    = (const float*)d_in[6];
    const float* proj_w = (const float*)d_in[7];
    const float* proj_b = (const float*)d_in[8];
    const float* ln2_g  = (const float*)d_in[9];
    const float* ln2_b  = (const float*)d_in[10];
    const float* fc1_w  = (const float*)d_in[11];
    const float* fc1_b  = (const float*)d_in[12];
    const float* fc2_w  = (const float*)d_in[13];
    const float* fc2_b  = (const float*)d_in[14];
    float* out = (float*)d_out;   // residual y lives here

    char* ws = (char*)d_ws;
    const size_t P1 = 51381248;          // q
    const size_t P2 = P1 + 51381248;     // k
    const size_t P3 = P2 + 51381248;     // Vt
    const size_t PW = P1 + 205520896;    // weights (after h region)

    short* xw    = (short*)ws;           // also attnO, xn2 (serial reuse)
    short* q     = (short*)(ws + P1);
    short* k     = (short*)(ws + P2);
    short* Vt    = (short*)(ws + P3);
    short* h     = (short*)(ws + P1);    // q/k/Vt dead by fc1
    short* wq    = (short*)(ws + PW);            // 49152 elems
    short* wp    = (short*)(ws + PW + 98304);    // 16384
    short* w1    = (short*)(ws + PW + 131072);   // 65536
    short* w2    = (short*)(ws + PW + 262144);   // 65536

    cvt_k<<<(49152 + 255) / 256, 256, 0, stream>>>(qkv_w, wq, 49152);
    cvt_k<<<(16384 + 255) / 256, 256, 0, stream>>>(proj_w, wp, 16384);
    cvt_k<<<(65536 + 255) / 256, 256, 0, stream>>>(fc1_w, w1, 65536);
    cvt_k<<<(65536 + 255) / 256, 256, 0, stream>>>(fc2_w, w2, 65536);

    ln_k<1><<<TOK / 4, 256, 0, stream>>>(x, ln1_g, ln1_b, xw);
    mgemm<0, 128><<<dim3(3, 1568), 256, 0, stream>>>(xw, wq, qkv_b, (void*)q,
                                                     nullptr, k, Vt);
    attn_k<<<2048, 256, 0, stream>>>(q, k, Vt, rpb, xw);
    mgemm<1, 128><<<dim3(1, 1568), 256, 0, stream>>>(xw, wp, proj_b, (void*)out,
                                                     x, nullptr, nullptr);
    ln_k<0><<<TOK / 4, 256, 0, stream>>>(out, ln2_g, ln2_b, xw);
    mgemm<2, 128><<<dim3(4, 1568), 256, 0, stream>>>(xw, w1, fc1_b, (void*)h,
                                                     nullptr, nullptr, nullptr);
    mgemm<3, 512><<<dim3(1, 1568), 256, 0, stream>>>(h, w2, fc2_b, (void*)out,
                                                     nullptr, nullptr, nullptr);
}